// Round 1
// baseline (1065.309 us; speedup 1.0000x reference)
//
#include <hip/hip_runtime.h>
#include <math.h>

// Problem constants (from reference)
#define VV 50257   // vocab
#define HH 512     // d_model
#define SS 512     // source length
#define BB 8       // batch
#define TT 64      // decode steps
#define MM (TT*BB) // 512 GEMM rows

// ---------------------------------------------------------------------------
// K1: mw[s,b] = dot(memory[s,b,:], W_prob)   -- one 64-lane block per (s,b)
// memory flat [S,B,H]: row (s*B+b) is contiguous length H.
// ---------------------------------------------------------------------------
__global__ void k_mw(const float* __restrict__ mem, const float* __restrict__ Wp,
                     float* __restrict__ mw) {
    int row = blockIdx.x;           // s*B + b
    int lane = threadIdx.x;         // 0..63
    const float* mp = mem + (size_t)row * HH;
    float acc = 0.f;
#pragma unroll
    for (int i = 0; i < HH / 64; i++)
        acc += mp[lane + 64 * i] * Wp[lane + 64 * i];
#pragma unroll
    for (int off = 32; off > 0; off >>= 1) acc += __shfl_down(acc, off);
    if (lane == 0) mw[row] = acc;
}

// ---------------------------------------------------------------------------
// K2: prob[t,b] = sigmoid( sum_s attn[b,t,s]*mw[s,b] + b_prob )
// one 64-lane block per (t*B+b)
// ---------------------------------------------------------------------------
__global__ void k_prob(const float* __restrict__ attn, const float* __restrict__ mw,
                       const float* __restrict__ bp, float* __restrict__ prob) {
    int r = blockIdx.x;             // t*B + b
    int t = r / BB, b = r % BB;
    int lane = threadIdx.x;
    const float* ap = attn + ((size_t)b * TT + t) * SS;
    float acc = 0.f;
#pragma unroll
    for (int i = 0; i < SS / 64; i++) {
        int s = lane + 64 * i;
        acc += ap[s] * mw[s * BB + b];
    }
#pragma unroll
    for (int off = 32; off > 0; off >>= 1) acc += __shfl_down(acc, off);
    if (lane == 0) prob[r] = 1.f / (1.f + expf(-(acc + bp[0])));
}

// ---------------------------------------------------------------------------
// K3: fp32 GEMM  C[m,v] = A[m,:]·W[:,v] + b_gen[v]
// A = decode_output as [M=512, H=512] (row m = t*B+b), W = W_gen [H, V].
// Writes raw logits into d_out. 64x64 tile, BK=16, 256 threads, 4x4/thread.
// ---------------------------------------------------------------------------
#define Bb_M 64
#define Bb_N 64
#define Bb_K 16
__global__ __launch_bounds__(256) void k_gemm(const float* __restrict__ A,
                                              const float* __restrict__ W,
                                              const float* __restrict__ bias,
                                              float* __restrict__ C) {
    __shared__ float As[Bb_K][Bb_M];
    __shared__ float Bs[Bb_K][Bb_N];
    int tid = threadIdx.x;
    int tx = tid & 15;          // 0..15 -> col group
    int ty = tid >> 4;          // 0..15 -> row group
    int row0 = blockIdx.y * Bb_M;
    int col0 = blockIdx.x * Bb_N;

    float acc[4][4] = {};

    for (int k0 = 0; k0 < HH; k0 += Bb_K) {
        // stage A tile 64x16 (1024 elems, 4/thread)
#pragma unroll
        for (int i = 0; i < 4; i++) {
            int idx = tid + i * 256;
            int ar = idx >> 4, ak = idx & 15;
            As[ak][ar] = A[(size_t)(row0 + ar) * HH + (k0 + ak)];
        }
        // stage B tile 16x64 (coalesced along v)
#pragma unroll
        for (int i = 0; i < 4; i++) {
            int idx = tid + i * 256;
            int bk = idx >> 6, bn = idx & 63;
            int col = col0 + bn;
            Bs[bk][bn] = (col < VV) ? W[(size_t)(k0 + bk) * VV + col] : 0.f;
        }
        __syncthreads();
#pragma unroll
        for (int k = 0; k < Bb_K; k++) {
            float4 a4 = *(const float4*)&As[k][ty * 4];
            float4 b4 = *(const float4*)&Bs[k][tx * 4];
            float a[4] = {a4.x, a4.y, a4.z, a4.w};
            float bb[4] = {b4.x, b4.y, b4.z, b4.w};
#pragma unroll
            for (int i = 0; i < 4; i++)
#pragma unroll
                for (int j = 0; j < 4; j++)
                    acc[i][j] += a[i] * bb[j];
        }
        __syncthreads();
    }

#pragma unroll
    for (int i = 0; i < 4; i++) {
        int r = row0 + ty * 4 + i;
#pragma unroll
        for (int j = 0; j < 4; j++) {
            int c = col0 + tx * 4 + j;
            if (c < VV) C[(size_t)r * VV + c] = acc[i][j] + bias[c];
        }
    }
}

// ---------------------------------------------------------------------------
// K4: fused per-row (t,b):
//   - build LDS hash of scatter-added copy mass (handles duplicate src ids)
//   - Zc = (V - D) + sum_distinct exp(a_v)
//   - gen softmax stats (max, Z) over the logits row in d_out
//   - rewrite row: log( p*exp(l-m)/Z + (1-p)*c_v/Zc ),  c_v = exp(a_v) or 1
// ---------------------------------------------------------------------------
#define HT 1024
__global__ __launch_bounds__(256) void k_final(const int* __restrict__ src,
                                               const float* __restrict__ attn,
                                               const float* __restrict__ prob,
                                               float* __restrict__ out) {
    __shared__ int   keys[HT];
    __shared__ float vals[HT];
    __shared__ float red[256];
    __shared__ int   s_D;
    __shared__ float s_m, s_Z, s_Zc;

    int r = blockIdx.x;           // t*B + b
    int t = r / BB, b = r % BB;
    int tid = threadIdx.x;

    for (int i = tid; i < HT; i += 256) { keys[i] = -1; vals[i] = 0.f; }
    if (tid == 0) s_D = 0;
    __syncthreads();

    // scatter attention mass into hash (duplicate-safe)
    const float* ap = attn + ((size_t)b * TT + t) * SS;
    for (int s = tid; s < SS; s += 256) {
        int idx = src[s * BB + b];
        float v = ap[s];
        unsigned h = ((unsigned)idx * 2654435761u) >> 22;   // 10-bit
        while (true) {
            int old = atomicCAS(&keys[h], -1, idx);
            if (old == -1 || old == idx) { atomicAdd(&vals[h], v); break; }
            h = (h + 1) & (HT - 1);
        }
    }
    __syncthreads();

    // Zc = (V - D) + sum exp(vals) over occupied slots
    float lsum = 0.f; int dloc = 0;
    for (int i = tid; i < HT; i += 256)
        if (keys[i] != -1) { lsum += expf(vals[i]); dloc++; }
    atomicAdd(&s_D, dloc);
    red[tid] = lsum; __syncthreads();
    for (int st = 128; st > 0; st >>= 1) {
        if (tid < st) red[tid] += red[tid + st];
        __syncthreads();
    }
    if (tid == 0) s_Zc = (float)(VV - s_D) + red[0];
    __syncthreads();

    float* rowp = out + (size_t)r * VV;

    // gen max
    float lmax = -INFINITY;
    for (int v = tid; v < VV; v += 256) lmax = fmaxf(lmax, rowp[v]);
    red[tid] = lmax; __syncthreads();
    for (int st = 128; st > 0; st >>= 1) {
        if (tid < st) red[tid] = fmaxf(red[tid], red[tid + st]);
        __syncthreads();
    }
    if (tid == 0) s_m = red[0];
    __syncthreads();
    float m = s_m;

    // gen denom
    float zloc = 0.f;
    for (int v = tid; v < VV; v += 256) zloc += expf(rowp[v] - m);
    red[tid] = zloc; __syncthreads();
    for (int st = 128; st > 0; st >>= 1) {
        if (tid < st) red[tid] += red[tid + st];
        __syncthreads();
    }
    if (tid == 0) s_Z = red[0];
    __syncthreads();

    float p = prob[r];
    float q = 1.f - p;
    float invZ = 1.f / s_Z;
    float invZc = 1.f / s_Zc;

    for (int v = tid; v < VV; v += 256) {
        float l = rowp[v];
        float g = expf(l - m) * invZ;
        // hash lookup: absent keys terminate at first empty slot
        unsigned h = ((unsigned)v * 2654435761u) >> 22;
        float c = 1.f;
        while (true) {
            int k = keys[h];
            if (k == -1) break;
            if (k == v) { c = expf(vals[h]); break; }
            h = (h + 1) & (HT - 1);
        }
        rowp[v] = logf(p * g + q * c * invZc);
    }
}

// ---------------------------------------------------------------------------
extern "C" void kernel_launch(void* const* d_in, const int* in_sizes, int n_in,
                              void* d_out, int out_size, void* d_ws, size_t ws_size,
                              hipStream_t stream) {
    const int*   src_full      = (const int*)d_in[0];   // [S,B]
    const float* decode_output = (const float*)d_in[1]; // [T,B,H]
    const float* decode_attn   = (const float*)d_in[2]; // [B,T,S]
    const float* memory        = (const float*)d_in[3]; // [S,B,H]
    const float* W_gen         = (const float*)d_in[4]; // [H,V]
    const float* b_gen         = (const float*)d_in[5]; // [V]
    const float* W_prob        = (const float*)d_in[6]; // [H]
    const float* b_prob        = (const float*)d_in[7]; // [1]
    float* out = (float*)d_out;                         // [T,B,V]

    float* ws   = (float*)d_ws;
    float* mw   = ws;            // S*B = 4096 floats
    float* prob = ws + SS * BB;  // T*B = 512 floats

    k_mw<<<SS * BB, 64, 0, stream>>>(memory, W_prob, mw);
    k_prob<<<TT * BB, 64, 0, stream>>>(decode_attn, mw, b_prob, prob);

    dim3 ggrid((VV + Bb_N - 1) / Bb_N, MM / Bb_M);      // 786 x 8
    k_gemm<<<ggrid, 256, 0, stream>>>(decode_output, W_gen, b_gen, out);

    k_final<<<TT * BB, 256, 0, stream>>>(src_full, decode_attn, prob, out);
}

// Round 2
// 588.343 us; speedup vs baseline: 1.8107x; 1.8107x over previous
//
#include <hip/hip_runtime.h>
#include <hip/hip_bf16.h>
#include <math.h>

#define VV 50257   // vocab
#define HH 512     // d_model
#define SS 512     // source length
#define BB 8       // batch
#define TT 64      // decode steps
#define MM (TT*BB) // 512 GEMM rows

typedef __bf16 bf16x2 __attribute__((ext_vector_type(2)));
typedef __bf16 bf16x4 __attribute__((ext_vector_type(4)));
typedef __bf16 bf16x8 __attribute__((ext_vector_type(8)));
typedef float  f32x4  __attribute__((ext_vector_type(4)));

// fp32 -> bf16 RNE (explicit, no reliance on cast lowering)
__device__ __forceinline__ __bf16 f2b(float f) {
    unsigned u = __builtin_bit_cast(unsigned, f);
    unsigned r = (u + 0x7fffu + ((u >> 16) & 1u)) >> 16;
    unsigned short s = (unsigned short)r;
    return __builtin_bit_cast(__bf16, s);
}

// ---------------------------------------------------------------------------
// K0: cast decode_output fp32 [512][512] -> bf16
// ---------------------------------------------------------------------------
__global__ __launch_bounds__(256) void k_cast(const float* __restrict__ A,
                                              __bf16* __restrict__ Ab) {
    int i = (blockIdx.x * 256 + threadIdx.x) * 4;
    float4 v = *(const float4*)&A[i];
    bf16x4 o = {f2b(v.x), f2b(v.y), f2b(v.z), f2b(v.w)};
    *(bf16x4*)&Ab[i] = o;
}

// ---------------------------------------------------------------------------
// K1: mw[s,b] = dot(memory[s,b,:], W_prob)
// ---------------------------------------------------------------------------
__global__ void k_mw(const float* __restrict__ mem, const float* __restrict__ Wp,
                     float* __restrict__ mw) {
    int row = blockIdx.x;
    int lane = threadIdx.x;
    const float* mp = mem + (size_t)row * HH;
    float acc = 0.f;
#pragma unroll
    for (int i = 0; i < HH / 64; i++)
        acc += mp[lane + 64 * i] * Wp[lane + 64 * i];
#pragma unroll
    for (int off = 32; off > 0; off >>= 1) acc += __shfl_down(acc, off);
    if (lane == 0) mw[row] = acc;
}

// ---------------------------------------------------------------------------
// K2: prob[t,b] = sigmoid( sum_s attn[b,t,s]*mw[s,b] + b_prob )
// ---------------------------------------------------------------------------
__global__ void k_prob(const float* __restrict__ attn, const float* __restrict__ mw,
                       const float* __restrict__ bp, float* __restrict__ prob) {
    int r = blockIdx.x;
    int t = r / BB, b = r % BB;
    int lane = threadIdx.x;
    const float* ap = attn + ((size_t)b * TT + t) * SS;
    float acc = 0.f;
#pragma unroll
    for (int i = 0; i < SS / 64; i++) {
        int s = lane + 64 * i;
        acc += ap[s] * mw[s * BB + b];
    }
#pragma unroll
    for (int off = 32; off > 0; off >>= 1) acc += __shfl_down(acc, off);
    if (lane == 0) prob[r] = 1.f / (1.f + expf(-(acc + bp[0])));
}

// ---------------------------------------------------------------------------
// K3: bf16 MFMA GEMM, 128x128 tile, BK=32, 256 threads (4 waves, each 64x64).
// Writes raw logits (+bias) to C and atomicAdds per-row sum(exp(logit)) to Z.
// W (fp32 [K][N]) is transposed into LDS as Bs[n][k] bf16; LDS row stride 36
// halves (18 dwords, odd*2) -> worst 2-way bank aliasing (free).
// ---------------------------------------------------------------------------
#define RS 36
__global__ __launch_bounds__(256) void k_gemm(const __bf16* __restrict__ Ab,
                                              const float* __restrict__ W,
                                              const float* __restrict__ bias,
                                              float* __restrict__ C,
                                              float* __restrict__ Zrow) {
    __shared__ __bf16 As[128 * RS];
    __shared__ __bf16 Bs[128 * RS];

    const int tid  = threadIdx.x;
    const int lane = tid & 63;
    const int wave = tid >> 6;
    const int wr = (wave >> 1) * 64;   // wave row origin in tile
    const int wc = (wave & 1) * 64;    // wave col origin in tile
    const int l15 = lane & 15;
    const int quad = lane >> 4;

    const int row0 = blockIdx.x * 128;
    const int col0 = blockIdx.y * 128;
    const bool full = (col0 + 128 <= VV);

    f32x4 acc[4][4] = {};  // [mt][nt]

    // per-thread staging constants
    const int am0 = tid >> 2;             // A: row within tile (chunk 0)
    const int akc = (tid & 3) * 8;        // A: k offset
    const int bn  = tid & 127;            // B: n within tile
    const int bkp0 = tid >> 7;            // B: k-pair base (0 or 1)

    for (int k0 = 0; k0 < HH; k0 += 32) {
        // ---- stage A: 128x32 bf16 (vector 8B copies)
#pragma unroll
        for (int j = 0; j < 2; j++) {
            int m = am0 + j * 64;
            const __bf16* gp = Ab + (size_t)(row0 + m) * HH + k0 + akc;
            bf16x4 lo = *(const bf16x4*)gp;
            bf16x4 hi = *(const bf16x4*)(gp + 4);
            *(bf16x4*)&As[m * RS + akc] = lo;
            *(bf16x4*)&As[m * RS + akc + 4] = hi;
        }
        // ---- stage B with transpose: W[k][n] -> Bs[n][k]
        int cg = col0 + bn;
#pragma unroll
        for (int j = 0; j < 8; j++) {
            int kp = bkp0 + j * 2;         // 0..15
            int k = kp * 2;
            float v0 = 0.f, v1 = 0.f;
            if (full || cg < VV) {
                const float* wp = W + (size_t)(k0 + k) * VV + cg;
                v0 = wp[0];
                v1 = wp[VV];
            }
            bf16x2 pk = {f2b(v0), f2b(v1)};
            *(bf16x2*)&Bs[bn * RS + k] = pk;
        }
        __syncthreads();

        bf16x8 af[4], bfv[4];
#pragma unroll
        for (int mt = 0; mt < 4; mt++) {
            const __bf16* p = &As[(wr + mt * 16 + l15) * RS + quad * 8];
            bf16x4 lo = *(const bf16x4*)p;
            bf16x4 hi = *(const bf16x4*)(p + 4);
            af[mt] = __builtin_shufflevector(lo, hi, 0, 1, 2, 3, 4, 5, 6, 7);
        }
#pragma unroll
        for (int nt = 0; nt < 4; nt++) {
            const __bf16* p = &Bs[(wc + nt * 16 + l15) * RS + quad * 8];
            bf16x4 lo = *(const bf16x4*)p;
            bf16x4 hi = *(const bf16x4*)(p + 4);
            bfv[nt] = __builtin_shufflevector(lo, hi, 0, 1, 2, 3, 4, 5, 6, 7);
        }
#pragma unroll
        for (int mt = 0; mt < 4; mt++)
#pragma unroll
            for (int nt = 0; nt < 4; nt++)
                acc[mt][nt] = __builtin_amdgcn_mfma_f32_16x16x32_bf16(
                    af[mt], bfv[nt], acc[mt][nt], 0, 0, 0);
        __syncthreads();
    }

    // ---- epilogue: bias add, store logits, per-row sum(exp) -> atomic Z
#pragma unroll
    for (int mt = 0; mt < 4; mt++) {
        float esum[4] = {0.f, 0.f, 0.f, 0.f};
#pragma unroll
        for (int nt = 0; nt < 4; nt++) {
            int c = col0 + wc + nt * 16 + l15;
            if (c < VV) {
                float bv = bias[c];
#pragma unroll
                for (int i = 0; i < 4; i++) {
                    int r = row0 + wr + mt * 16 + quad * 4 + i;
                    float l = acc[mt][nt][i] + bv;
                    C[(size_t)r * VV + c] = l;
                    esum[i] += __expf(l);
                }
            }
        }
#pragma unroll
        for (int i = 0; i < 4; i++) {
            float e = esum[i];
            e += __shfl_xor(e, 1);
            e += __shfl_xor(e, 2);
            e += __shfl_xor(e, 4);
            e += __shfl_xor(e, 8);
            if (l15 == 0) {
                int r = row0 + wr + mt * 16 + quad * 4 + i;
                atomicAdd(&Zrow[r], e);
            }
        }
    }
}

// ---------------------------------------------------------------------------
// K4: single-pass finalize, chunked over columns.
//   out = log( p*exp(l)/Z + (1-p)*c_v/Zc ),  c_v = exp(hash[v]) or 1
// ---------------------------------------------------------------------------
#define HT 1024
#define CHUNK 12565
__global__ __launch_bounds__(256) void k_final(const int* __restrict__ src,
                                               const float* __restrict__ attn,
                                               const float* __restrict__ prob,
                                               const float* __restrict__ Zrow,
                                               float* __restrict__ out) {
    __shared__ int   keys[HT];
    __shared__ float vals[HT];
    __shared__ float red[256];
    __shared__ int   s_D;
    __shared__ float s_Zc;

    int r = blockIdx.y;           // t*B + b
    int t = r / BB, b = r % BB;
    int tid = threadIdx.x;

    for (int i = tid; i < HT; i += 256) { keys[i] = -1; vals[i] = 0.f; }
    if (tid == 0) s_D = 0;
    __syncthreads();

    // scatter attention mass into hash (duplicate-safe)
    const float* ap = attn + ((size_t)b * TT + t) * SS;
    for (int s = tid; s < SS; s += 256) {
        int idx = src[s * BB + b];
        float v = ap[s];
        unsigned h = ((unsigned)idx * 2654435761u) >> 22;
        while (true) {
            int old = atomicCAS(&keys[h], -1, idx);
            if (old == -1 || old == idx) { atomicAdd(&vals[h], v); break; }
            h = (h + 1) & (HT - 1);
        }
    }
    __syncthreads();

    // Zc = (V - D) + sum exp(vals) over occupied slots
    float lsum = 0.f; int dloc = 0;
    for (int i = tid; i < HT; i += 256)
        if (keys[i] != -1) { lsum += __expf(vals[i]); dloc++; }
    atomicAdd(&s_D, dloc);
    red[tid] = lsum; __syncthreads();
    for (int st = 128; st > 0; st >>= 1) {
        if (tid < st) red[tid] += red[tid + st];
        __syncthreads();
    }
    if (tid == 0) s_Zc = (float)(VV - s_D) + red[0];
    __syncthreads();

    float p = prob[r];
    float q = 1.f - p;
    float pinvZ = p / Zrow[r];
    float qinvZc = q / s_Zc;

    int c0 = blockIdx.x * CHUNK;
    int c1 = c0 + CHUNK; if (c1 > VV) c1 = VV;
    float* rowp = out + (size_t)r * VV;

    for (int v = c0 + tid; v < c1; v += 256) {
        float l = rowp[v];
        float g = __expf(l);
        unsigned h = ((unsigned)v * 2654435761u) >> 22;
        float c = 1.f;
        while (true) {
            int k = keys[h];
            if (k == -1) break;
            if (k == v) { c = __expf(vals[h]); break; }
            h = (h + 1) & (HT - 1);
        }
        rowp[v] = __logf(pinvZ * g + qinvZc * c);
    }
}

// ---------------------------------------------------------------------------
extern "C" void kernel_launch(void* const* d_in, const int* in_sizes, int n_in,
                              void* d_out, int out_size, void* d_ws, size_t ws_size,
                              hipStream_t stream) {
    const int*   src_full      = (const int*)d_in[0];   // [S,B]
    const float* decode_output = (const float*)d_in[1]; // [T,B,H]
    const float* decode_attn   = (const float*)d_in[2]; // [B,T,S]
    const float* memory        = (const float*)d_in[3]; // [S,B,H]
    const float* W_gen         = (const float*)d_in[4]; // [H,V]
    const float* b_gen         = (const float*)d_in[5]; // [V]
    const float* W_prob        = (const float*)d_in[6]; // [H]
    const float* b_prob        = (const float*)d_in[7]; // [1]
    float* out = (float*)d_out;                         // [T,B,V]

    float* ws   = (float*)d_ws;
    float* mw   = ws;                 // 4096 floats
    float* prob = ws + 4096;          // 512
    float* Z    = ws + 4608;          // 512
    __bf16* Ab  = (__bf16*)(ws + 5120);  // 512*512 bf16

    k_cast<<<MM * HH / (256 * 4), 256, 0, stream>>>(decode_output, Ab);
    k_mw<<<SS * BB, 64, 0, stream>>>(memory, W_prob, mw);
    k_prob<<<TT * BB, 64, 0, stream>>>(decode_attn, mw, b_prob, prob);
    hipMemsetAsync(Z, 0, MM * sizeof(float), stream);

    dim3 ggrid(MM / 128, (VV + 127) / 128);   // (4, 393)
    k_gemm<<<ggrid, 256, 0, stream>>>(Ab, W_gen, b_gen, out, Z);

    dim3 fgrid((VV + CHUNK - 1) / CHUNK, MM); // (4, 512)
    k_final<<<fgrid, 256, 0, stream>>>(src_full, decode_attn, prob, Z, out);
}

// Round 3
// 407.876 us; speedup vs baseline: 2.6118x; 1.4425x over previous
//
#include <hip/hip_runtime.h>
#include <hip/hip_bf16.h>
#include <math.h>

#define VV 50257   // vocab
#define VP 50304   // vocab padded to multiple of 128
#define HH 512     // d_model
#define SS 512     // source length
#define BB 8       // batch
#define TT 64      // decode steps
#define MM (TT*BB) // 512 GEMM rows

typedef __bf16 bf16x2 __attribute__((ext_vector_type(2)));
typedef __bf16 bf16x4 __attribute__((ext_vector_type(4)));
typedef __bf16 bf16x8 __attribute__((ext_vector_type(8)));
typedef float  f32x4  __attribute__((ext_vector_type(4)));

// fp32 -> bf16 RNE
__device__ __forceinline__ __bf16 f2b(float f) {
    unsigned u = __builtin_bit_cast(unsigned, f);
    unsigned r = (u + 0x7fffu + ((u >> 16) & 1u)) >> 16;
    unsigned short s = (unsigned short)r;
    return __builtin_bit_cast(__bf16, s);
}

// async global->LDS, 16B per lane; lds base must be wave-uniform
__device__ __forceinline__ void gl2lds16(const void* g, void* l) {
    __builtin_amdgcn_global_load_lds(
        (const __attribute__((address_space(1))) unsigned*)g,
        (__attribute__((address_space(3))) unsigned*)l, 16, 0, 0);
}

// ---------------------------------------------------------------------------
// K0a: cast decode_output fp32 [512*512] -> bf16
// ---------------------------------------------------------------------------
__global__ __launch_bounds__(256) void k_castA(const float* __restrict__ A,
                                               __bf16* __restrict__ Ab) {
    int i = (blockIdx.x * 256 + threadIdx.x) * 4;
    float4 v = *(const float4*)&A[i];
    bf16x4 o = {f2b(v.x), f2b(v.y), f2b(v.z), f2b(v.w)};
    *(bf16x4*)&Ab[i] = o;
}

// ---------------------------------------------------------------------------
// K0b: W fp32 [HH][VV] -> Wt bf16 [VP][HH] (transpose via LDS tile 64x64)
// ---------------------------------------------------------------------------
__global__ __launch_bounds__(256) void k_castWT(const float* __restrict__ W,
                                                __bf16* __restrict__ Wt) {
    __shared__ float tile[64][65];
    int n0 = blockIdx.x * 64;
    int k0 = blockIdx.y * 64;
    int tid = threadIdx.x;
#pragma unroll
    for (int i = 0; i < 16; i++) {
        int idx = tid + i * 256;
        int kk = idx >> 6, nn = idx & 63;
        int n = n0 + nn;
        tile[kk][nn] = (n < VV) ? W[(size_t)(k0 + kk) * VV + n] : 0.f;
    }
    __syncthreads();
#pragma unroll
    for (int i = 0; i < 8; i++) {
        int idx = tid + i * 256;
        int nn = idx >> 5, kp = idx & 31;
        bf16x2 o = {f2b(tile[2 * kp][nn]), f2b(tile[2 * kp + 1][nn])};
        *(bf16x2*)&Wt[(size_t)(n0 + nn) * HH + k0 + 2 * kp] = o;
    }
}

// ---------------------------------------------------------------------------
// K1: mw[s,b] = dot(memory[s,b,:], W_prob)
// ---------------------------------------------------------------------------
__global__ void k_mw(const float* __restrict__ mem, const float* __restrict__ Wp,
                     float* __restrict__ mw) {
    int row = blockIdx.x;
    int lane = threadIdx.x;
    const float* mp = mem + (size_t)row * HH;
    float acc = 0.f;
#pragma unroll
    for (int i = 0; i < HH / 64; i++)
        acc += mp[lane + 64 * i] * Wp[lane + 64 * i];
#pragma unroll
    for (int off = 32; off > 0; off >>= 1) acc += __shfl_down(acc, off);
    if (lane == 0) mw[row] = acc;
}

// ---------------------------------------------------------------------------
// K2: prob[t,b] = sigmoid( sum_s attn[b,t,s]*mw[s,b] + b_prob )
// ---------------------------------------------------------------------------
__global__ void k_prob(const float* __restrict__ attn, const float* __restrict__ mw,
                       const float* __restrict__ bp, float* __restrict__ prob) {
    int r = blockIdx.x;
    int t = r / BB, b = r % BB;
    int lane = threadIdx.x;
    const float* ap = attn + ((size_t)b * TT + t) * SS;
    float acc = 0.f;
#pragma unroll
    for (int i = 0; i < SS / 64; i++) {
        int s = lane + 64 * i;
        acc += ap[s] * mw[s * BB + b];
    }
#pragma unroll
    for (int off = 32; off > 0; off >>= 1) acc += __shfl_down(acc, off);
    if (lane == 0) prob[r] = 1.f / (1.f + expf(-(acc + bp[0])));
}

// ---------------------------------------------------------------------------
// K3: MFMA GEMM, both operands bf16 k-contiguous; global_load_lds staging.
// 128x128 tile, BK=32, 4 waves each 64x64. Logits+bias -> C, sum(exp) -> Z.
// ---------------------------------------------------------------------------
__global__ __launch_bounds__(256) void k_gemm2(const __bf16* __restrict__ Ab,
                                               const __bf16* __restrict__ Wt,
                                               const float* __restrict__ bias,
                                               float* __restrict__ C,
                                               float* __restrict__ Zrow) {
    __shared__ __bf16 As[128 * 32];   // row-major, row stride 32 bf16 = 64B
    __shared__ __bf16 Bs[128 * 32];

    const int tid  = threadIdx.x;
    const int lane = tid & 63;
    const int wave = tid >> 6;
    const int wr = (wave >> 1) * 64;
    const int wc = (wave & 1) * 64;
    const int l15 = lane & 15;
    const int quad = lane >> 4;
    const int r_in_seg = lane >> 2;   // 0..15
    const int chunk = lane & 3;       // 0..3 (16B chunks of a 64B row)

    const int row0 = blockIdx.x * 128;
    const int col0 = blockIdx.y * 128;

    f32x4 acc[4][4] = {};

    for (int k0 = 0; k0 < HH; k0 += 32) {
        // stage A: 8 segs of 16 rows x 64B; this wave does segs 2w,2w+1
#pragma unroll
        for (int q = 0; q < 2; q++) {
            int seg = wave * 2 + q;
            int ar = seg * 16 + r_in_seg;
            gl2lds16(Ab + (size_t)(row0 + ar) * HH + k0 + chunk * 8,
                     &As[seg * 512]);
        }
#pragma unroll
        for (int q = 0; q < 2; q++) {
            int seg = wave * 2 + q;
            int br = seg * 16 + r_in_seg;
            gl2lds16(Wt + (size_t)(col0 + br) * HH + k0 + chunk * 8,
                     &Bs[seg * 512]);
        }
        __syncthreads();

        bf16x8 af[4], bfv[4];
#pragma unroll
        for (int mt = 0; mt < 4; mt++)
            af[mt] = *(const bf16x8*)&As[(wr + mt * 16 + l15) * 32 + quad * 8];
#pragma unroll
        for (int nt = 0; nt < 4; nt++)
            bfv[nt] = *(const bf16x8*)&Bs[(wc + nt * 16 + l15) * 32 + quad * 8];
#pragma unroll
        for (int mt = 0; mt < 4; mt++)
#pragma unroll
            for (int nt = 0; nt < 4; nt++)
                acc[mt][nt] = __builtin_amdgcn_mfma_f32_16x16x32_bf16(
                    af[mt], bfv[nt], acc[mt][nt], 0, 0, 0);
        __syncthreads();
    }

#pragma unroll
    for (int mt = 0; mt < 4; mt++) {
        float esum[4] = {0.f, 0.f, 0.f, 0.f};
#pragma unroll
        for (int nt = 0; nt < 4; nt++) {
            int c = col0 + wc + nt * 16 + l15;
            if (c < VV) {
                float bv = bias[c];
#pragma unroll
                for (int i = 0; i < 4; i++) {
                    int r = row0 + wr + mt * 16 + quad * 4 + i;
                    float l = acc[mt][nt][i] + bv;
                    C[(size_t)r * VV + c] = l;
                    esum[i] += __expf(l);
                }
            }
        }
#pragma unroll
        for (int i = 0; i < 4; i++) {
            float e = esum[i];
            e += __shfl_xor(e, 1);
            e += __shfl_xor(e, 2);
            e += __shfl_xor(e, 4);
            e += __shfl_xor(e, 8);
            if (l15 == 0) {
                int r = row0 + wr + mt * 16 + quad * 4 + i;
                atomicAdd(&Zrow[r], e);
            }
        }
    }
}

// ---------------------------------------------------------------------------
// K3-fallback (round-2 validated path, fp32 W transposed in-kernel) —
// used only if ws_size can't hold Wt.
// ---------------------------------------------------------------------------
#define RS 36
__global__ __launch_bounds__(256) void k_gemm_fb(const __bf16* __restrict__ Ab,
                                                 const float* __restrict__ W,
                                                 const float* __restrict__ bias,
                                                 float* __restrict__ C,
                                                 float* __restrict__ Zrow) {
    __shared__ __bf16 As[128 * RS];
    __shared__ __bf16 Bs[128 * RS];
    const int tid  = threadIdx.x;
    const int lane = tid & 63;
    const int wave = tid >> 6;
    const int wr = (wave >> 1) * 64;
    const int wc = (wave & 1) * 64;
    const int l15 = lane & 15;
    const int quad = lane >> 4;
    const int row0 = blockIdx.x * 128;
    const int col0 = blockIdx.y * 128;
    const bool full = (col0 + 128 <= VV);
    f32x4 acc[4][4] = {};
    const int am0 = tid >> 2;
    const int akc = (tid & 3) * 8;
    const int bn  = tid & 127;
    const int bkp0 = tid >> 7;

    for (int k0 = 0; k0 < HH; k0 += 32) {
#pragma unroll
        for (int j = 0; j < 2; j++) {
            int m = am0 + j * 64;
            const __bf16* gp = Ab + (size_t)(row0 + m) * HH + k0 + akc;
            bf16x4 lo = *(const bf16x4*)gp;
            bf16x4 hi = *(const bf16x4*)(gp + 4);
            *(bf16x4*)&As[m * RS + akc] = lo;
            *(bf16x4*)&As[m * RS + akc + 4] = hi;
        }
        int cg = col0 + bn;
#pragma unroll
        for (int j = 0; j < 8; j++) {
            int kp = bkp0 + j * 2;
            int k = kp * 2;
            float v0 = 0.f, v1 = 0.f;
            if (full || cg < VV) {
                const float* wp = W + (size_t)(k0 + k) * VV + cg;
                v0 = wp[0];
                v1 = wp[VV];
            }
            bf16x2 pk = {f2b(v0), f2b(v1)};
            *(bf16x2*)&Bs[bn * RS + k] = pk;
        }
        __syncthreads();
        bf16x8 af[4], bfv[4];
#pragma unroll
        for (int mt = 0; mt < 4; mt++) {
            const __bf16* p = &As[(wr + mt * 16 + l15) * RS + quad * 8];
            bf16x4 lo = *(const bf16x4*)p;
            bf16x4 hi = *(const bf16x4*)(p + 4);
            af[mt] = __builtin_shufflevector(lo, hi, 0, 1, 2, 3, 4, 5, 6, 7);
        }
#pragma unroll
        for (int nt = 0; nt < 4; nt++) {
            const __bf16* p = &Bs[(wc + nt * 16 + l15) * RS + quad * 8];
            bf16x4 lo = *(const bf16x4*)p;
            bf16x4 hi = *(const bf16x4*)(p + 4);
            bfv[nt] = __builtin_shufflevector(lo, hi, 0, 1, 2, 3, 4, 5, 6, 7);
        }
#pragma unroll
        for (int mt = 0; mt < 4; mt++)
#pragma unroll
            for (int nt = 0; nt < 4; nt++)
                acc[mt][nt] = __builtin_amdgcn_mfma_f32_16x16x32_bf16(
                    af[mt], bfv[nt], acc[mt][nt], 0, 0, 0);
        __syncthreads();
    }
#pragma unroll
    for (int mt = 0; mt < 4; mt++) {
        float esum[4] = {0.f, 0.f, 0.f, 0.f};
#pragma unroll
        for (int nt = 0; nt < 4; nt++) {
            int c = col0 + wc + nt * 16 + l15;
            if (c < VV) {
                float bv = bias[c];
#pragma unroll
                for (int i = 0; i < 4; i++) {
                    int r = row0 + wr + mt * 16 + quad * 4 + i;
                    float l = acc[mt][nt][i] + bv;
                    C[(size_t)r * VV + c] = l;
                    esum[i] += __expf(l);
                }
            }
        }
#pragma unroll
        for (int i = 0; i < 4; i++) {
            float e = esum[i];
            e += __shfl_xor(e, 1);
            e += __shfl_xor(e, 2);
            e += __shfl_xor(e, 4);
            e += __shfl_xor(e, 8);
            if (l15 == 0) {
                int r = row0 + wr + mt * 16 + quad * 4 + i;
                atomicAdd(&Zrow[r], e);
            }
        }
    }
}

// ---------------------------------------------------------------------------
// K4: single-pass finalize with bitmap-gated hash lookup.
// ---------------------------------------------------------------------------
#define HT 1024
#define NBW 1572   // ceil(VV/32)
#define CHUNK 6283
__global__ __launch_bounds__(256) void k_final(const int* __restrict__ src,
                                               const float* __restrict__ attn,
                                               const float* __restrict__ prob,
                                               const float* __restrict__ Zrow,
                                               float* __restrict__ out) {
    __shared__ int      keys[HT];
    __shared__ float    vals[HT];
    __shared__ unsigned bmap[NBW];
    __shared__ float    red[256];
    __shared__ int      s_D;
    __shared__ float    s_Zc;

    int r = blockIdx.y;
    int t = r / BB, b = r % BB;
    int tid = threadIdx.x;

    for (int i = tid; i < HT; i += 256) { keys[i] = -1; vals[i] = 0.f; }
    for (int i = tid; i < NBW; i += 256) bmap[i] = 0u;
    if (tid == 0) s_D = 0;
    __syncthreads();

    const float* ap = attn + ((size_t)b * TT + t) * SS;
    for (int s = tid; s < SS; s += 256) {
        int idx = src[s * BB + b];
        float v = ap[s];
        unsigned h = ((unsigned)idx * 2654435761u) >> 22;
        while (true) {
            int old = atomicCAS(&keys[h], -1, idx);
            if (old == -1 || old == idx) { atomicAdd(&vals[h], v); break; }
            h = (h + 1) & (HT - 1);
        }
    }
    __syncthreads();

    float lsum = 0.f; int dloc = 0;
    for (int i = tid; i < HT; i += 256) {
        int k = keys[i];
        if (k != -1) {
            lsum += __expf(vals[i]); dloc++;
            atomicOr(&bmap[(unsigned)k >> 5], 1u << (k & 31));
        }
    }
    atomicAdd(&s_D, dloc);
    red[tid] = lsum; __syncthreads();
    for (int st = 128; st > 0; st >>= 1) {
        if (tid < st) red[tid] += red[tid + st];
        __syncthreads();
    }
    if (tid == 0) s_Zc = (float)(VV - s_D) + red[0];
    __syncthreads();

    float p = prob[r];
    float pinvZ = p / Zrow[r];
    float qinvZc = (1.f - p) / s_Zc;

    int c0 = blockIdx.x * CHUNK;
    int c1 = c0 + CHUNK; if (c1 > VV) c1 = VV;
    float* rowp = out + (size_t)r * VV;

    for (int v = c0 + tid; v < c1; v += 256) {
        float l = rowp[v];
        float c = 1.f;
        bool hit = (bmap[v >> 5] >> (v & 31)) & 1u;
        if (hit) {
            unsigned h = ((unsigned)v * 2654435761u) >> 22;
            while (true) {
                int k = keys[h];
                if (k == v) { c = __expf(vals[h]); break; }
                if (k == -1) break;
                h = (h + 1) & (HT - 1);
            }
        }
        rowp[v] = __logf(pinvZ * __expf(l) + qinvZc * c);
    }
}

// ---------------------------------------------------------------------------
extern "C" void kernel_launch(void* const* d_in, const int* in_sizes, int n_in,
                              void* d_out, int out_size, void* d_ws, size_t ws_size,
                              hipStream_t stream) {
    const int*   src_full      = (const int*)d_in[0];   // [S,B]
    const float* decode_output = (const float*)d_in[1]; // [T,B,H]
    const float* decode_attn   = (const float*)d_in[2]; // [B,T,S]
    const float* memory        = (const float*)d_in[3]; // [S,B,H]
    const float* W_gen         = (const float*)d_in[4]; // [H,V]
    const float* b_gen         = (const float*)d_in[5]; // [V]
    const float* W_prob        = (const float*)d_in[6]; // [H]
    const float* b_prob        = (const float*)d_in[7]; // [1]
    float* out = (float*)d_out;                         // [T,B,V]

    float* ws   = (float*)d_ws;
    float* mw   = ws;                        // 4096 floats
    float* prob = ws + 4096;                 // 512
    float* Z    = ws + 4608;                 // 512
    __bf16* Ab  = (__bf16*)(ws + 5120);      // 512*512 bf16 = 131072 floats
    __bf16* Wt  = (__bf16*)(ws + 5120 + 131072);  // VP*HH bf16

    size_t need = (size_t)(5120 + 131072) * sizeof(float) + (size_t)VP * HH * 2;

    k_castA<<<MM * HH / (256 * 4), 256, 0, stream>>>(decode_output, Ab);
    k_mw<<<SS * BB, 64, 0, stream>>>(memory, W_prob, mw);
    k_prob<<<TT * BB, 64, 0, stream>>>(decode_attn, mw, b_prob, prob);
    hipMemsetAsync(Z, 0, MM * sizeof(float), stream);

    if (ws_size >= need) {
        dim3 tgrid(VP / 64, HH / 64);            // (786, 8)
        k_castWT<<<tgrid, 256, 0, stream>>>(W_gen, Wt);
        dim3 ggrid(MM / 128, VP / 128);          // (4, 393)
        k_gemm2<<<ggrid, 256, 0, stream>>>(Ab, Wt, b_gen, out, Z);
    } else {
        dim3 ggrid(MM / 128, VP / 128);
        k_gemm_fb<<<ggrid, 256, 0, stream>>>(Ab, W_gen, b_gen, out, Z);
    }

    dim3 fgrid((VV + CHUNK - 1) / CHUNK, MM);    // (8, 512)
    k_final<<<fgrid, 256, 0, stream>>>(src_full, decode_attn, prob, Z, out);
}

// Round 4
// 380.479 us; speedup vs baseline: 2.7999x; 1.0720x over previous
//
#include <hip/hip_runtime.h>
#include <hip/hip_bf16.h>
#include <math.h>

#define VV 50257   // vocab
#define VP 50304   // vocab padded to multiple of 128 (and 16)
#define HH 512     // d_model
#define SS 512     // source length
#define BB 8       // batch
#define TT 64      // decode steps
#define MM (TT*BB) // 512 GEMM rows

typedef __bf16 bf16x2 __attribute__((ext_vector_type(2)));
typedef __bf16 bf16x4 __attribute__((ext_vector_type(4)));
typedef __bf16 bf16x8 __attribute__((ext_vector_type(8)));
typedef float  f32x4  __attribute__((ext_vector_type(4)));

// fp32 -> bf16 RNE
__device__ __forceinline__ __bf16 f2b(float f) {
    unsigned u = __builtin_bit_cast(unsigned, f);
    unsigned r = (u + 0x7fffu + ((u >> 16) & 1u)) >> 16;
    unsigned short s = (unsigned short)r;
    return __builtin_bit_cast(__bf16, s);
}

// async global->LDS, 16B per lane; lds base must be wave-uniform
__device__ __forceinline__ void gl2lds16(const void* g, void* l) {
    __builtin_amdgcn_global_load_lds(
        (const __attribute__((address_space(1))) unsigned*)g,
        (__attribute__((address_space(3))) unsigned*)l, 16, 0, 0);
}

// ---------------------------------------------------------------------------
// K0a: cast decode_output fp32 [512*512] -> bf16
// ---------------------------------------------------------------------------
__global__ __launch_bounds__(256) void k_castA(const float* __restrict__ A,
                                               __bf16* __restrict__ Ab) {
    int i = (blockIdx.x * 256 + threadIdx.x) * 4;
    float4 v = *(const float4*)&A[i];
    bf16x4 o = {f2b(v.x), f2b(v.y), f2b(v.z), f2b(v.w)};
    *(bf16x4*)&Ab[i] = o;
}

// ---------------------------------------------------------------------------
// K0b: W fp32 [HH][VV] -> Wt bf16 [VP][HH] (transpose via LDS tile 64x64)
// ---------------------------------------------------------------------------
__global__ __launch_bounds__(256) void k_castWT(const float* __restrict__ W,
                                                __bf16* __restrict__ Wt) {
    __shared__ float tile[64][65];
    int n0 = blockIdx.x * 64;
    int k0 = blockIdx.y * 64;
    int tid = threadIdx.x;
#pragma unroll
    for (int i = 0; i < 16; i++) {
        int idx = tid + i * 256;
        int kk = idx >> 6, nn = idx & 63;
        int n = n0 + nn;
        tile[kk][nn] = (n < VV) ? W[(size_t)(k0 + kk) * VV + n] : 0.f;
    }
    __syncthreads();
#pragma unroll
    for (int i = 0; i < 8; i++) {
        int idx = tid + i * 256;
        int nn = idx >> 5, kp = idx & 31;
        bf16x2 o = {f2b(tile[2 * kp][nn]), f2b(tile[2 * kp + 1][nn])};
        *(bf16x2*)&Wt[(size_t)(n0 + nn) * HH + k0 + 2 * kp] = o;
    }
}

// ---------------------------------------------------------------------------
// K1: mw[s,b] = dot(memory[s,b,:], W_prob)
// ---------------------------------------------------------------------------
__global__ void k_mw(const float* __restrict__ mem, const float* __restrict__ Wp,
                     float* __restrict__ mw) {
    int row = blockIdx.x;
    int lane = threadIdx.x;
    const float* mp = mem + (size_t)row * HH;
    float acc = 0.f;
#pragma unroll
    for (int i = 0; i < HH / 64; i++)
        acc += mp[lane + 64 * i] * Wp[lane + 64 * i];
#pragma unroll
    for (int off = 32; off > 0; off >>= 1) acc += __shfl_down(acc, off);
    if (lane == 0) mw[row] = acc;
}

// ---------------------------------------------------------------------------
// K2: prob[t,b] = sigmoid( sum_s attn[b,t,s]*mw[s,b] + b_prob )
// ---------------------------------------------------------------------------
__global__ void k_prob(const float* __restrict__ attn, const float* __restrict__ mw,
                       const float* __restrict__ bp, float* __restrict__ prob) {
    int r = blockIdx.x;
    int t = r / BB, b = r % BB;
    int lane = threadIdx.x;
    const float* ap = attn + ((size_t)b * TT + t) * SS;
    float acc = 0.f;
#pragma unroll
    for (int i = 0; i < SS / 64; i++) {
        int s = lane + 64 * i;
        acc += ap[s] * mw[s * BB + b];
    }
#pragma unroll
    for (int off = 32; off > 0; off >>= 1) acc += __shfl_down(acc, off);
    if (lane == 0) prob[r] = 1.f / (1.f + expf(-(acc + bp[0])));
}

// ---------------------------------------------------------------------------
// K3: MFMA GEMM 128x128 tile, BK=64, double-buffered, fragment-order LDS
// (conflict-free ds_read: lane L reads bytes seg*2048 + h*1024 + 16*L).
// One barrier per k-iter; DMA for iter k+1 issued right after barrier(k),
// its latency hidden behind compute(k).
// Epilogue: bias add, logits -> bf16 ws (or fp32 d_out), LDS-reduced Z atomics.
// ---------------------------------------------------------------------------
template<bool BF16OUT>
__global__ __launch_bounds__(256, 2) void k_gemm3(const __bf16* __restrict__ Ab,
                                                  const __bf16* __restrict__ Wt,
                                                  const float* __restrict__ bias,
                                                  float* __restrict__ Cf,
                                                  __bf16* __restrict__ Cb,
                                                  float* __restrict__ Zrow) {
    __shared__ __bf16 As[2][8192];   // 8 segs x (8 chunks x 16 rows x 8 bf16) = 16 KB
    __shared__ __bf16 Bs[2][8192];
    __shared__ float zred[128];

    const int tid  = threadIdx.x;
    const int lane = tid & 63;
    const int wave = tid >> 6;
    const int l15  = lane & 15;
    const int quad = lane >> 4;
    const int wr = (wave >> 1) * 64;
    const int wc = (wave & 1) * 64;
    const int row0 = blockIdx.x * 128;
    const int col0 = blockIdx.y * 128;

    // staging: wave w handles segs {2w, 2w+1} of both operands; per seg 2 DMA
    // halves j=0,1. Lane L loads global (row=seg*16+l15, k=(j*4+quad)*8..+8)
    // into LDS slot seg*2048B + j*1024B + 16B*L  (fragment order).
    size_t offA[2][2], offB[2][2];
#pragma unroll
    for (int q = 0; q < 2; q++)
#pragma unroll
        for (int j = 0; j < 2; j++) {
            int seg = 2 * wave + q;
            offA[q][j] = (size_t)(row0 + seg * 16 + l15) * HH + (j * 4 + quad) * 8;
            offB[q][j] = (size_t)(col0 + seg * 16 + l15) * HH + (j * 4 + quad) * 8;
        }

#define STAGE(buf, k0)                                                        \
    do {                                                                      \
        _Pragma("unroll") for (int q = 0; q < 2; q++)                         \
        _Pragma("unroll") for (int j = 0; j < 2; j++) {                       \
            int seg = 2 * wave + q;                                           \
            gl2lds16(Ab + offA[q][j] + (k0), &As[buf][seg * 1024 + j * 512]); \
            gl2lds16(Wt + offB[q][j] + (k0), &Bs[buf][seg * 1024 + j * 512]); \
        }                                                                     \
    } while (0)

    f32x4 acc[4][4] = {};

    STAGE(0, 0);
    for (int it = 0; it < 8; ++it) {
        __syncthreads();                        // drains buf[it&1] DMAs
        if (it != 7) STAGE((it + 1) & 1, (it + 1) * 64);
        const __bf16* Al = &As[it & 1][0];
        const __bf16* Bl = &Bs[it & 1][0];
#pragma unroll
        for (int h = 0; h < 2; ++h) {
            bf16x8 af[4], bfv[4];
#pragma unroll
            for (int mt = 0; mt < 4; mt++)
                af[mt] = *(const bf16x8*)&Al[((wr >> 4) + mt) * 1024 + h * 512 + lane * 8];
#pragma unroll
            for (int nt = 0; nt < 4; nt++)
                bfv[nt] = *(const bf16x8*)&Bl[((wc >> 4) + nt) * 1024 + h * 512 + lane * 8];
#pragma unroll
            for (int mt = 0; mt < 4; mt++)
#pragma unroll
                for (int nt = 0; nt < 4; nt++)
                    acc[mt][nt] = __builtin_amdgcn_mfma_f32_16x16x32_bf16(
                        af[mt], bfv[nt], acc[mt][nt], 0, 0, 0);
        }
    }
#undef STAGE

    __syncthreads();
    if (tid < 128) zred[tid] = 0.f;
    __syncthreads();

#pragma unroll
    for (int mt = 0; mt < 4; mt++) {
        float esum[4] = {0.f, 0.f, 0.f, 0.f};
#pragma unroll
        for (int nt = 0; nt < 4; nt++) {
            int c = col0 + wc + nt * 16 + l15;
            if (c < VV) {
                float bv = bias[c];
#pragma unroll
                for (int i = 0; i < 4; i++) {
                    int r = row0 + wr + mt * 16 + quad * 4 + i;
                    float l = acc[mt][nt][i] + bv;
                    if (BF16OUT) Cb[(size_t)r * VP + c] = f2b(l);
                    else         Cf[(size_t)r * VV + c] = l;
                    esum[i] += __expf(l);
                }
            }
        }
#pragma unroll
        for (int i = 0; i < 4; i++) {
            float e = esum[i];
            e += __shfl_xor(e, 1);
            e += __shfl_xor(e, 2);
            e += __shfl_xor(e, 4);
            e += __shfl_xor(e, 8);
            if (l15 == 0)
                atomicAdd(&zred[wr + mt * 16 + quad * 4 + i], e);
        }
    }
    __syncthreads();
    if (tid < 128) atomicAdd(&Zrow[row0 + tid], zred[tid]);
}

// ---------------------------------------------------------------------------
// K4 shared preamble: build per-row copy-mass hash + bitmap + Zc in LDS.
// ---------------------------------------------------------------------------
#define HT 1024
#define NBW 1572   // ceil(VV/32)

__device__ __forceinline__ void build_hash(const int* __restrict__ src,
                                           const float* __restrict__ ap,
                                           int b, int tid,
                                           int* keys, float* vals, unsigned* bmap,
                                           float* red, int* s_D, float* s_Zc) {
    for (int i = tid; i < HT; i += 256) { keys[i] = -1; vals[i] = 0.f; }
    for (int i = tid; i < NBW; i += 256) bmap[i] = 0u;
    if (tid == 0) *s_D = 0;
    __syncthreads();

    for (int s = tid; s < SS; s += 256) {
        int idx = src[s * BB + b];
        float v = ap[s];
        unsigned h = ((unsigned)idx * 2654435761u) >> 22;
        while (true) {
            int old = atomicCAS(&keys[h], -1, idx);
            if (old == -1 || old == idx) { atomicAdd(&vals[h], v); break; }
            h = (h + 1) & (HT - 1);
        }
    }
    __syncthreads();

    float lsum = 0.f; int dloc = 0;
    for (int i = tid; i < HT; i += 256) {
        int k = keys[i];
        if (k != -1) {
            lsum += __expf(vals[i]); dloc++;
            atomicOr(&bmap[(unsigned)k >> 5], 1u << (k & 31));
        }
    }
    atomicAdd(s_D, dloc);
    red[tid] = lsum; __syncthreads();
    for (int st = 128; st > 0; st >>= 1) {
        if (tid < st) red[tid] += red[tid + st];
        __syncthreads();
    }
    if (tid == 0) *s_Zc = (float)(VV - *s_D) + red[0];
    __syncthreads();
}

// ---------------------------------------------------------------------------
// K4a: finalize from bf16 padded logits (vector loads), write fp32 out.
// ---------------------------------------------------------------------------
#define CHUNKV 6288  // VP/8 blocks-of-8: 8 col-chunks per row
__global__ __launch_bounds__(256) void k_final_v(const int* __restrict__ src,
                                                 const float* __restrict__ attn,
                                                 const float* __restrict__ prob,
                                                 const float* __restrict__ Zrow,
                                                 const __bf16* __restrict__ LG,
                                                 float* __restrict__ out) {
    __shared__ int      keys[HT];
    __shared__ float    vals[HT];
    __shared__ unsigned bmap[NBW];
    __shared__ float    red[256];
    __shared__ int      s_D;
    __shared__ float    s_Zc;

    int r = blockIdx.y;
    int t = r / BB, b = r % BB;
    int tid = threadIdx.x;
    const float* ap = attn + ((size_t)b * TT + t) * SS;
    build_hash(src, ap, b, tid, keys, vals, bmap, red, &s_D, &s_Zc);

    float p = prob[r];
    float pinvZ = p / Zrow[r];
    float qinvZc = (1.f - p) / s_Zc;

    int c0 = blockIdx.x * CHUNKV;
    const __bf16* lrow = LG + (size_t)r * VP + c0;
    float* orow = out + (size_t)r * VV;

    for (int v0 = tid * 8; v0 < CHUNKV; v0 += 2048) {
        bf16x8 l8 = *(const bf16x8*)&lrow[v0];
#pragma unroll
        for (int e = 0; e < 8; e++) {
            int v = c0 + v0 + e;
            if (v < VV) {
                float l = (float)l8[e];
                float c = 1.f;
                if ((bmap[v >> 5] >> (v & 31)) & 1u) {
                    unsigned h = ((unsigned)v * 2654435761u) >> 22;
                    while (true) {
                        int k = keys[h];
                        if (k == v) { c = __expf(vals[h]); break; }
                        if (k == -1) break;
                        h = (h + 1) & (HT - 1);
                    }
                }
                orow[v] = __logf(pinvZ * __expf(l) + qinvZc * c);
            }
        }
    }
}

// ---------------------------------------------------------------------------
// K4b: fallback — finalize fp32 logits in-place in d_out (R3-validated path).
// ---------------------------------------------------------------------------
#define CHUNKS 6283
__global__ __launch_bounds__(256) void k_final_s(const int* __restrict__ src,
                                                 const float* __restrict__ attn,
                                                 const float* __restrict__ prob,
                                                 const float* __restrict__ Zrow,
                                                 float* __restrict__ out) {
    __shared__ int      keys[HT];
    __shared__ float    vals[HT];
    __shared__ unsigned bmap[NBW];
    __shared__ float    red[256];
    __shared__ int      s_D;
    __shared__ float    s_Zc;

    int r = blockIdx.y;
    int t = r / BB, b = r % BB;
    int tid = threadIdx.x;
    const float* ap = attn + ((size_t)b * TT + t) * SS;
    build_hash(src, ap, b, tid, keys, vals, bmap, red, &s_D, &s_Zc);

    float p = prob[r];
    float pinvZ = p / Zrow[r];
    float qinvZc = (1.f - p) / s_Zc;

    int c0 = blockIdx.x * CHUNKS;
    int c1 = c0 + CHUNKS; if (c1 > VV) c1 = VV;
    float* rowp = out + (size_t)r * VV;

    for (int v = c0 + tid; v < c1; v += 256) {
        float l = rowp[v];
        float c = 1.f;
        if ((bmap[v >> 5] >> (v & 31)) & 1u) {
            unsigned h = ((unsigned)v * 2654435761u) >> 22;
            while (true) {
                int k = keys[h];
                if (k == v) { c = __expf(vals[h]); break; }
                if (k == -1) break;
                h = (h + 1) & (HT - 1);
            }
        }
        rowp[v] = __logf(pinvZ * __expf(l) + qinvZc * c);
    }
}

// ---------------------------------------------------------------------------
extern "C" void kernel_launch(void* const* d_in, const int* in_sizes, int n_in,
                              void* d_out, int out_size, void* d_ws, size_t ws_size,
                              hipStream_t stream) {
    const int*   src_full      = (const int*)d_in[0];   // [S,B]
    const float* decode_output = (const float*)d_in[1]; // [T,B,H]
    const float* decode_attn   = (const float*)d_in[2]; // [B,T,S]
    const float* memory        = (const float*)d_in[3]; // [S,B,H]
    const float* W_gen         = (const float*)d_in[4]; // [H,V]
    const float* b_gen         = (const float*)d_in[5]; // [V]
    const float* W_prob        = (const float*)d_in[6]; // [H]
    const float* b_prob        = (const float*)d_in[7]; // [1]
    float* out = (float*)d_out;                         // [T,B,V]

    float* ws   = (float*)d_ws;
    float* mw   = ws;                        // 4096 floats
    float* prob = ws + 4096;                 // 512
    float* Z    = ws + 4608;                 // 512
    __bf16* Ab  = (__bf16*)(ws + 5120);      // 512*512 bf16 (512 KB = 131072 float slots)
    __bf16* Wt  = (__bf16*)(ws + 5120 + 131072);   // VP*HH bf16 (51.5 MB)
    __bf16* LG  = Wt + (size_t)VP * HH;            // MM*VP bf16 (51.5 MB)

    size_t base_b = (size_t)(5120 + 131072) * sizeof(float);
    size_t wt_b   = (size_t)VP * HH * 2;
    size_t lg_b   = (size_t)MM * VP * 2;
    bool full = ws_size >= base_b + wt_b + lg_b;

    k_castA<<<MM * HH / (256 * 4), 256, 0, stream>>>(decode_output, Ab);
    k_mw<<<SS * BB, 64, 0, stream>>>(memory, W_prob, mw);
    k_prob<<<TT * BB, 64, 0, stream>>>(decode_attn, mw, b_prob, prob);
    hipMemsetAsync(Z, 0, MM * sizeof(float), stream);

    dim3 tgrid(VP / 64, HH / 64);            // (786, 8)
    k_castWT<<<tgrid, 256, 0, stream>>>(W_gen, Wt);

    dim3 ggrid(MM / 128, VP / 128);          // (4, 393)
    if (full) {
        k_gemm3<true><<<ggrid, 256, 0, stream>>>(Ab, Wt, b_gen, nullptr, LG, Z);
        dim3 fgrid(VP / CHUNKV, MM);         // (8, 512)
        k_final_v<<<fgrid, 256, 0, stream>>>(src_full, decode_attn, prob, Z, LG, out);
    } else {
        k_gemm3<false><<<ggrid, 256, 0, stream>>>(Ab, Wt, b_gen, out, nullptr, Z);
        dim3 fgrid((VV + CHUNKS - 1) / CHUNKS, MM);  // (8, 512)
        k_final_s<<<fgrid, 256, 0, stream>>>(src_full, decode_attn, prob, Z, out);
    }
}